// Round 8
// baseline (121.867 us; speedup 1.0000x reference)
//
#include <hip/hip_runtime.h>

// PrimalDualNetwork: 10-iter Chambolle-Pock ROF on 2048x2048 fp32.
// R8 = R7 math + occupancy restructure for barrier-stall overlap:
//  - NT=512 (8 waves), tile 64x48, plane 68x88 => 4 blocks/CU = 4
//    independent barrier groups (R7: 2 blocks of 16 waves, VALUBusy 52%,
//    ~48% barrier stall). LDS 39KB: sXT fp32 23.9K + sQV fp16 12.0K +
//    sQH3 sidebar 3.1K (primal only reads ELEMENT 3 of the left unit;
//    full sQH plane in R7 was waste).
//  - launch_bounds(512,4): R5-measured semantics (2nd arg ~ blocks/CU)
//    -> 8 waves/EU -> 64-VGPR cap; naive state ~60 (qV not kept in regs,
//    xi fp16). Spill tripwire: WRITE_SIZE >> 16MB.
//  - grid.y = ceil(2048/48) = 43; demasking (sw=0 off-image) makes the
//    partial last row-band correct; output store row-guarded.
//  - Cone guard: active iff rem >= d, d = max(9-li, li-57, 8-lc, lc-75, 0)
//    (tail units 100). Junk at plane edges/row-wrap stays >=1 px outside
//    the shrinking need-set (diagonal-margin argument, validated R5-R7).

namespace {
constexpr int M = 2048, N = 2048;
constexpr float SIGMA     = 1.0f / (7.0f * 0.01f);
constexpr float TAU       = 0.01f;
constexpr float TAUIS     = TAU * (7.0f * 0.01f);    // tau/sigma (q-scaled div)
constexpr float LT        = 4.0f * 0.01f;
constexpr float INV_DEN   = 1.0f / (1.0f + 4.0f * 0.01f);
constexpr int TW = 64, TH = 48;     // output tile
constexpr int PC = 88;              // plane cols (12 + 64 + 12)
constexpr int PR = 68;              // plane rows (10 + 48 + 10)
constexpr int UPR = 22;             // float4 units per row == PC/4
constexpr int PROC = 67;            // rows 0..66 processed (67 read-only)
constexpr int NU = PROC * UPR;      // 1474
constexpr int NT = 512;             // 8 waves
constexpr int NPASS = 3;            // 3*512 = 1536 >= NU
constexpr int GY = (M + TH - 1) / TH;   // 43
} // namespace

typedef _Float16 h4 __attribute__((ext_vector_type(4)));

__device__ inline h4 h4splat(float v) {
    _Float16 s = (_Float16)v;
    return (h4){s, s, s, s};
}
__device__ inline int imax(int a, int b) { return a > b ? a : b; }

__global__ __launch_bounds__(NT, 4) void pd_fused(
    const float* __restrict__ img, float* __restrict__ out,
    const float* __restrict__ w1p, const float* __restrict__ w2p)
{
    __shared__ __align__(16) float    sXT[PR * PC];    // 23936 B
    __shared__ __align__(16) _Float16 sQV[PR * PC];    // 11968 B
    __shared__ __align__(16) _Float16 sQH3[1536];      //  3072 B (qH[3] per unit)

    const int tid  = threadIdx.x;
    const int lane = tid & 63;
    const int c0 = blockIdx.x * TW, r0 = blockIdx.y * TH;
    const int gr0 = r0 - 10, gc0 = c0 - 12;
    const float w1 = w1p[0], w2 = w2p[0];

    // per-pass invariants (lean: bF + cone threshold only)
    int bF_[NPASS], dth_[NPASS];
    #pragma unroll
    for (int p = 0; p < NPASS; ++p) {
        int u = tid + p * NT;
        int li = u / UPR, uj = u - li * UPR;
        int lc = uj * 4;
        bF_[p] = u * 4;
        int d = imax(imax(9 - li, li - (TH + 9)), imax(8 - lc, lc - 75));
        d = imax(d, 0);
        if (u >= NU) d = 100;
        dth_[p] = d;
    }

    // ---- stage img -> sXT (rows 0..67; 0 outside image) ----
    #pragma unroll
    for (int p = 0; p < NPASS; ++p) {
        int su = tid + p * NT;
        if (su < PR * UPR) {
            int li = su / UPR, uj = su - li * UPR;
            int gi = gr0 + li, gj = gc0 + uj * 4;
            float4 v = make_float4(0.f, 0.f, 0.f, 0.f);
            if ((unsigned)gi < (unsigned)M && (unsigned)gj <= (unsigned)(N - 4))
                v = *(const float4*)&img[(size_t)gi * N + gj];
            *(float4*)&sXT[su * 4] = v;
        }
    }
    __syncthreads();

    // register state (qV NOT kept: re-read own sQV in primal)
    float xr[NPASS][4], xt[NPASS][4];
    h4 xi[NPASS], yh[NPASS], yv[NPASS], swh[NPASS], swv[NPASS], qH[NPASS];

    // ---- init (== dual(0)): masked sigma*w, y0, q0 ----
    #pragma unroll
    for (int p = 0; p < NPASS; ++p) {
        int u = tid + p * NT, bF = bF_[p];
        float4 c = make_float4(0.f, 0.f, 0.f, 0.f);
        if (u < NU) c = *(const float4*)&sXT[bF];
        float rr = __shfl_down(c.x, 1, 64);
        if (u < NU) {
            int li = u / UPR;
            int gi = gr0 + li, gjb = gc0 + (u - li * UPR) * 4;
            if (lane == 63) rr = sXT[bF + 4];
            float4 dn = *(const float4*)&sXT[bF + PC];
            float ca[4] = {c.x, c.y, c.z, c.w};
            float da[4] = {dn.x, dn.y, dn.z, dn.w};
            bool rok = (unsigned)gi < (unsigned)M;
            bool vok = rok && (gi < M - 1);
            h4 qv;
            #pragma unroll
            for (int l = 0; l < 4; ++l) {
                int gj = gjb + l;
                bool cok = (unsigned)gj < (unsigned)N;
                bool hok = rok && cok && (gj < N - 1);
                bool vk  = vok && cok;
                float nxt = (l < 3) ? ca[l + 1] : rr;
                float gh = hok ? nxt - ca[l] : 0.f;
                float gv = vk  ? da[l] - ca[l] : 0.f;
                float wh = fmaf(w2, __expf(-fabsf(gh)), w1);
                float wv = fmaf(w2, __expf(-fabsf(gv)), w1);
                float y0h = fminf(fmaxf(gh * fmaf(SIGMA, wh, 1.f), -1.f), 1.f);
                float y0v = fminf(fmaxf(gv * fmaf(SIGMA, wv, 1.f), -1.f), 1.f);
                float sh = hok ? SIGMA * wh : 0.f;
                float sv = vk  ? SIGMA * wv : 0.f;
                yh[p][l]  = (_Float16)y0h;  yv[p][l]  = (_Float16)y0v;
                swh[p][l] = (_Float16)sh;   swv[p][l] = (_Float16)sv;
                qH[p][l]  = (_Float16)(sh * y0h);
                qv[l]     = (_Float16)(sv * y0v);
                xr[p][l] = ca[l]; xt[p][l] = ca[l];
                xi[p][l] = (_Float16)ca[l];
            }
            *(h4*)&sQV[bF] = qv;
            sQH3[u] = qH[p][3];
        }
    }
    __syncthreads();

    // ---- dual(t>=1): y = clamp(y + sw*grad(xt)); q = sw*y ----
    auto dual = [&](int rem) {
        #pragma unroll
        for (int p = 0; p < NPASS; ++p) {
            float rr = __shfl_down(xt[p][0], 1, 64);   // unconditional (exec-safe)
            if (rem >= dth_[p]) {
                int bF = bF_[p];
                if (lane == 63) rr = sXT[bF + 4];
                float4 dn = *(const float4*)&sXT[bF + PC];
                float da[4] = {dn.x, dn.y, dn.z, dn.w};
                h4 ghh, gvh;
                #pragma unroll
                for (int l = 0; l < 4; ++l) {
                    float nxt = (l < 3) ? xt[p][l + 1] : rr;
                    ghh[l] = (_Float16)(nxt - xt[p][l]);   // fp32 sub, pk-cvt
                    gvh[l] = (_Float16)(da[l] - xt[p][l]);
                }
                h4 nh = yh[p] + swh[p] * ghh;   // sw=0 masks borders/off-image
                h4 nv = yv[p] + swv[p] * gvh;
                nh = __builtin_elementwise_min(__builtin_elementwise_max(nh, h4splat(-1.f)), h4splat(1.f));
                nv = __builtin_elementwise_min(__builtin_elementwise_max(nv, h4splat(-1.f)), h4splat(1.f));
                yh[p] = nh; yv[p] = nv;
                h4 qh = swh[p] * nh;            // q = sigma*w*y
                h4 qv = swv[p] * nv;
                qH[p] = qh;
                *(h4*)&sQV[bF] = qv;
                sQH3[bF >> 2] = qh[3];
            }
        }
    };

    // ---- primal: x = (x + (tau/sigma)*div(q) + lt*img)/(1+lt); xt=1.5x-0.5xo
    auto primal = [&](int rem) {
        #pragma unroll
        for (int p = 0; p < NPASS; ++p) {
            if (rem >= dth_[p]) {
                int bF = bF_[p];
                int bu = (bF >= UPR * 4) ? bF - PC : bF;   // row-0 junk tolerated
                h4 qvu = *(const h4*)&sQV[bu];
                h4 qv  = *(const h4*)&sQV[bF];
                _Float16 qhl = sQH3[imax((bF >> 2) - 1, 0)];  // left unit's qH[3]
                h4 qsh;                                        // qH shifted right 1
                qsh[0] = qhl; qsh[1] = qH[p][0]; qsh[2] = qH[p][1]; qsh[3] = qH[p][2];
                h4 dvg = (qH[p] - qsh) + (qv - qvu);           // v_pk_sub/add_f16
                float xtv[4];
                #pragma unroll
                for (int l = 0; l < 4; ++l) {
                    float dv = (float)dvg[l];
                    float xo = xr[p][l];
                    float xn = (fmaf(TAUIS, dv, xo) + LT * (float)xi[p][l]) * INV_DEN;
                    xr[p][l] = xn;
                    float v = fmaf(0.5f, xn - xo, xn);   // 1.5x - 0.5xo
                    xt[p][l] = v; xtv[l] = v;
                }
                *(float4*)&sXT[bF] = make_float4(xtv[0], xtv[1], xtv[2], xtv[3]);
            }
        }
    };

    primal(9);                 // t=0 (dual(0) fused into init)
    __syncthreads();
    #pragma unroll 1
    for (int t = 1; t < 10; ++t) {
        int rem = 9 - t;
        dual(rem);
        __syncthreads();
        primal(rem);
        __syncthreads();
    }

    // ---- output xt(9): plane rows 10..57, cols 12..75 (row-guarded) ----
    #pragma unroll
    for (int v = tid; v < TH * (TW / 4); v += NT) {
        int row = v >> 4;            // 0..47
        int cu  = v & 15;            // 0..15
        int gi = r0 + row;
        if (gi < M) {
            float4 o = *(const float4*)&sXT[(10 + row) * PC + 12 + 4 * cu];
            *(float4*)&out[(size_t)gi * N + (c0 + 4 * cu)] = o;
        }
    }
}

extern "C" void kernel_launch(void* const* d_in, const int* in_sizes, int n_in,
                              void* d_out, int out_size, void* d_ws, size_t ws_size,
                              hipStream_t stream)
{
    const float* img = (const float*)d_in[0];
    const float* w1  = (const float*)d_in[1];
    const float* w2  = (const float*)d_in[2];
    float* out = (float*)d_out;

    dim3 grid(N / TW, GY);   // 32 x 43
    pd_fused<<<grid, NT, 0, stream>>>(img, out, w1, w2);
}

// Round 9
// 116.862 us; speedup vs baseline: 1.0428x; 1.0428x over previous
//
#include <hip/hip_runtime.h>

// PrimalDualNetwork: 10-iter Chambolle-Pock ROF on 2048x2048 fp32.
// R9 = R8 structure (NT=512, tile 64x48, 4 blocks/CU, cone guard,
// demasked sw) + packed-fp16 xt plane:
//  - sXT16 (_Float16): dual's grads become pure v_pk_sub_f16 via
//    v_alignbit element shifts; kills 8 fp32 subs + 8 cvts per unit-iter
//    (R8's fattest VALU block). LDS 39.4 -> 27.0 KB.
//  - x (primal state) stays fp32 in registers — the precision-critical
//    path. xt is only consumed through fp16-rounded gradients; injected
//    err ~1e-3/iter into y, bounded ~2e-3 on output vs 0.0177 threshold.
//  - Final primal (t=9) stores fp32 xtv DIRECTLY to global (epilogue and
//    its LDS round-trip deleted; output not fp16-rounded).
//  - launch_bounds(512,4): R5 lesson (2nd arg ~ blocks/CU; tighter caps
//    VGPRs -> scratch spills -> WRITE_SIZE blow-up = tripwire).

namespace {
constexpr int M = 2048, N = 2048;
constexpr float SIGMA     = 1.0f / (7.0f * 0.01f);
constexpr float TAUIS     = 0.01f * (7.0f * 0.01f);  // tau/sigma
constexpr float LT        = 4.0f * 0.01f;
constexpr float INV_DEN   = 1.0f / (1.0f + 4.0f * 0.01f);
constexpr int TW = 64, TH = 48;     // output tile
constexpr int PC = 88;              // plane cols (12 + 64 + 12)
constexpr int PR = 68;              // plane rows (10 + 48 + 10)
constexpr int UPR = 22;             // h4 units per row == PC/4
constexpr int PROC = 67;            // rows 0..66 processed (67 read-only)
constexpr int NU = PROC * UPR;      // 1474
constexpr int NT = 512;             // 8 waves
constexpr int NPASS = 3;            // 3*512 >= NU
constexpr int GY = (M + TH - 1) / TH;   // 43
} // namespace

typedef _Float16 h4 __attribute__((ext_vector_type(4)));
typedef unsigned uint32;

__device__ inline h4 h4splat(float v) {
    _Float16 s = (_Float16)v;
    return (h4){s, s, s, s};
}
__device__ inline int imax(int a, int b) { return a > b ? a : b; }
__device__ inline uint32 abit(uint32 hi, uint32 lo) {
    return __builtin_amdgcn_alignbit(hi, lo, 16);
}
__device__ inline h4 clamp1(h4 v) {
    return __builtin_elementwise_min(
               __builtin_elementwise_max(v, h4splat(-1.f)), h4splat(1.f));
}

__global__ __launch_bounds__(NT, 4) void pd_fused(
    const float* __restrict__ img, float* __restrict__ out,
    const float* __restrict__ w1p, const float* __restrict__ w2p)
{
    __shared__ __align__(16) _Float16 sXT16[PR * PC];  // 11968 B (xt, fp16)
    __shared__ __align__(16) _Float16 sQV[PR * PC];    // 11968 B
    __shared__ __align__(16) _Float16 sQH3[1536];      //  3072 B (qH[3]/unit)

    const int tid  = threadIdx.x;
    const int lane = tid & 63;
    const int c0 = blockIdx.x * TW, r0 = blockIdx.y * TH;
    const int gr0 = r0 - 10, gc0 = c0 - 12;
    const float w1 = w1p[0], w2 = w2p[0];

    // cone deactivation threshold per pass (active iff rem >= d)
    int dth_[NPASS];
    #pragma unroll
    for (int p = 0; p < NPASS; ++p) {
        int u = tid + p * NT;
        int li = u / UPR, lc = (u - li * UPR) * 4;
        int d = imax(imax(9 - li, li - (TH + 9)), imax(8 - lc, lc - 75));
        d = imax(d, 0);
        if (u >= NU) d = 100;
        dth_[p] = d;
    }

    // ---- stage img -> sXT16 (fp16; 0 outside image) ----
    #pragma unroll
    for (int p = 0; p < NPASS; ++p) {
        int su = tid + p * NT;
        if (su < PR * UPR) {
            int li = su / UPR, uj = su - li * UPR;
            int gi = gr0 + li, gj = gc0 + uj * 4;
            float4 v = make_float4(0.f, 0.f, 0.f, 0.f);
            if ((unsigned)gi < (unsigned)M && (unsigned)gj <= (unsigned)(N - 4))
                v = *(const float4*)&img[(size_t)gi * N + gj];
            h4 h; h[0] = (_Float16)v.x; h[1] = (_Float16)v.y;
                  h[2] = (_Float16)v.z; h[3] = (_Float16)v.w;
            *(h4*)&sXT16[su * 4] = h;
        }
    }
    __syncthreads();

    // register state: x fp32 (precision-critical), rest packed fp16
    float xr[NPASS][4];
    h4 xt16[NPASS], xi16[NPASS], yh[NPASS], yv[NPASS],
       swh[NPASS], swv[NPASS], qH[NPASS];

    // ---- init (== dual(0)): masked sigma*w, y0, q0 ----
    #pragma unroll
    for (int p = 0; p < NPASS; ++p) {
        int u = tid + p * NT;
        if (u < NU) {
            int bF = u * 4;
            int li = u / UPR;
            int gi = gr0 + li, gjb = gc0 + (u - li * UPR) * 4;
            h4 c16 = *(const h4*)&sXT16[bF];
            uint32 rrp = *(const uint32*)&sXT16[bF + 4];
            h4 dn = *(const h4*)&sXT16[bF + PC];
            uint2 xu = __builtin_bit_cast(uint2, c16);
            h4 xsh = __builtin_bit_cast(h4,
                         make_uint2(abit(xu.y, xu.x), abit(rrp, xu.y)));
            bool rok = (unsigned)gi < (unsigned)M;
            bool vok = rok && (gi < M - 1);
            h4 qv;
            #pragma unroll
            for (int l = 0; l < 4; ++l) {
                int gj = gjb + l;
                bool cok = (unsigned)gj < (unsigned)N;
                bool hok = rok && cok && (gj < N - 1);
                bool vk  = vok && cok;
                float ghf = hok ? (float)xsh[l] - (float)c16[l] : 0.f;
                float gvf = vk  ? (float)dn[l]  - (float)c16[l] : 0.f;
                float wh = fmaf(w2, __expf(-fabsf(ghf)), w1);
                float wv = fmaf(w2, __expf(-fabsf(gvf)), w1);
                float y0h = fminf(fmaxf(ghf * fmaf(SIGMA, wh, 1.f), -1.f), 1.f);
                float y0v = fminf(fmaxf(gvf * fmaf(SIGMA, wv, 1.f), -1.f), 1.f);
                float sh = hok ? SIGMA * wh : 0.f;
                float sv = vk  ? SIGMA * wv : 0.f;
                yh[p][l]  = (_Float16)y0h;  yv[p][l]  = (_Float16)y0v;
                swh[p][l] = (_Float16)sh;   swv[p][l] = (_Float16)sv;
                qH[p][l]  = (_Float16)(sh * y0h);
                qv[l]     = (_Float16)(sv * y0v);
                xr[p][l]  = (float)c16[l];
            }
            xi16[p] = c16; xt16[p] = c16;
            *(h4*)&sQV[bF] = qv;
            sQH3[u] = qH[p][3];
        }
    }
    __syncthreads();

    // ---- dual(t>=1): fully packed; y = clamp(y + sw*grad16(xt)); q = sw*y
    auto dual = [&](int rem) {
        #pragma unroll
        for (int p = 0; p < NPASS; ++p) {
            uint2 xu = __builtin_bit_cast(uint2, xt16[p]);
            uint32 rrp = __shfl_down(xu.x, 1, 64);   // hoisted (exec-safe)
            if (rem >= dth_[p]) {
                int bF = (tid + p * NT) * 4;
                if (lane == 63) rrp = *(const uint32*)&sXT16[bF + 4];
                h4 dn = *(const h4*)&sXT16[bF + PC];
                h4 xsh = __builtin_bit_cast(h4,
                             make_uint2(abit(xu.y, xu.x), abit(rrp, xu.y)));
                h4 ghh = xsh - xt16[p];              // v_pk_sub_f16
                h4 gvh = dn  - xt16[p];
                h4 nh = clamp1(yh[p] + swh[p] * ghh);  // sw=0 masks borders
                h4 nv = clamp1(yv[p] + swv[p] * gvh);
                yh[p] = nh; yv[p] = nv;
                h4 qh = swh[p] * nh;                 // q = sigma*w*y
                h4 qv = swv[p] * nv;
                qH[p] = qh;
                *(h4*)&sQV[bF] = qv;
                sQH3[bF >> 2] = qh[3];
            }
        }
    };

    // ---- primal: x = (x + (tau/sigma)*div(q) + lt*img)/(1+lt);
    //      xt = 1.5x - 0.5xo. last: store fp32 to global, skip LDS. ----
    auto primal = [&](int rem, bool last) {
        #pragma unroll
        for (int p = 0; p < NPASS; ++p) {
            if (rem >= dth_[p]) {
                int u = tid + p * NT, bF = u * 4;
                int bu = (bF >= UPR * 4) ? bF - PC : bF;  // row-0 junk tolerated
                h4 qvu = *(const h4*)&sQV[bu];
                h4 qv  = *(const h4*)&sQV[bF];
                uint32 qhl = *(const unsigned short*)&sQH3[imax(u - 1, 0)];
                uint2 qu = __builtin_bit_cast(uint2, qH[p]);
                h4 qsh = __builtin_bit_cast(h4,
                             make_uint2(abit(qu.x, qhl << 16), abit(qu.y, qu.x)));
                h4 dvg = (qH[p] - qsh) + (qv - qvu);     // v_pk_sub/add_f16
                float xtv[4];
                #pragma unroll
                for (int l = 0; l < 4; ++l) {
                    float dv = (float)dvg[l];
                    float xo = xr[p][l];
                    float xn = (fmaf(TAUIS, dv, xo) + LT * (float)xi16[p][l]) * INV_DEN;
                    xr[p][l] = xn;
                    xtv[l] = fmaf(0.5f, xn - xo, xn);    // 1.5x - 0.5xo
                }
                if (!last) {
                    h4 nx; nx[0] = (_Float16)xtv[0]; nx[1] = (_Float16)xtv[1];
                           nx[2] = (_Float16)xtv[2]; nx[3] = (_Float16)xtv[3];
                    xt16[p] = nx;
                    *(h4*)&sXT16[bF] = nx;
                } else {
                    int li = u / UPR, uj = u - li * UPR;
                    int gi = gr0 + li;
                    if (li >= 10 && uj >= 3 && uj <= 18 && gi < M) {
                        *(float4*)&out[(size_t)gi * N + (gc0 + uj * 4)] =
                            make_float4(xtv[0], xtv[1], xtv[2], xtv[3]);
                    }
                }
            }
        }
    };

    primal(9, false);          // t=0 (dual(0) fused into init)
    __syncthreads();
    #pragma unroll 1
    for (int t = 1; t < 10; ++t) {
        int rem = 9 - t;
        dual(rem);
        __syncthreads();
        primal(rem, t == 9);
        __syncthreads();
    }
}

extern "C" void kernel_launch(void* const* d_in, const int* in_sizes, int n_in,
                              void* d_out, int out_size, void* d_ws, size_t ws_size,
                              hipStream_t stream)
{
    const float* img = (const float*)d_in[0];
    const float* w1  = (const float*)d_in[1];
    const float* w2  = (const float*)d_in[2];
    float* out = (float*)d_out;

    dim3 grid(N / TW, GY);   // 32 x 43
    pd_fused<<<grid, NT, 0, stream>>>(img, out, w1, w2);
}